// Round 10
// baseline (197.642 us; speedup 1.0000x reference)
//
#include <hip/hip_runtime.h>
#include <math.h>

// NeRF two-pass renderer. One wave (64 lanes) per ray; 4 waves per block.
// B=65536 rays, KC=64 coarse, KF=64 fine, HID=32.
//
// R10 = R8 backbone (W2 in LDS, VGPR=32, occ 77%) + R9's validated pieces:
//  - pos_c via 6-step shuffle binary search over monotone g (no histogram,
//    no LDS atomics, no fences, no zM overlay).
//  - z2n via DPP wave_shl:1 of z0 (no extra LDS read).
//  - W2 staged as float4[32]; mlp reads forced to ds_read_b128 (w2 rows and
//    a/c quads); f32x2 halves extracted in-register.
//  - per-lane global loads (uc, uf, uj) hoisted to kernel top.
//  - kept from R8: 6-step guardless searchsorted, bitonic with ds_swizzle
//    immediates, quad-transposed output reductions, direct-exp alphas,
//    f16-packed merge payload.

typedef float f32x2 __attribute__((ext_vector_type(2)));
typedef _Float16 f16x2v __attribute__((ext_vector_type(2)));
typedef _Float16 f16x4v __attribute__((ext_vector_type(4)));

__device__ __forceinline__ float fast_rcp(float x) { return __builtin_amdgcn_rcpf(x); }
__device__ __forceinline__ float fsigmoid(float x) { return fast_rcp(1.0f + __expf(-x)); }

// compiler-only fence: no HW barrier; preserves LDS program order per wave
__device__ __forceinline__ void wave_fence() {
    asm volatile("" ::: "memory");
    __builtin_amdgcn_wave_barrier();
}

// DPP move: result = valid(src lane) ? shuffled x : oldv   (bound_ctrl=0)
template <int CTRL, int RMASK>
__device__ __forceinline__ float dpp_f(float x, float oldv) {
    return __int_as_float(__builtin_amdgcn_update_dpp(
        __float_as_int(oldv), __float_as_int(x), CTRL, RMASK, 0xf, false));
}
template <int OFF>
__device__ __forceinline__ float swz_f(float x) {
    return __int_as_float(__builtin_amdgcn_ds_swizzle(__float_as_int(x), OFF));
}

// inclusive multiply-scan over 64 lanes
__device__ __forceinline__ float scan_mul(float x) {
    x *= dpp_f<0x111, 0xf>(x, 1.0f);  // row_shr:1
    x *= dpp_f<0x112, 0xf>(x, 1.0f);  // row_shr:2
    x *= dpp_f<0x114, 0xf>(x, 1.0f);  // row_shr:4
    x *= dpp_f<0x118, 0xf>(x, 1.0f);  // row_shr:8
    x *= dpp_f<0x142, 0xa>(x, 1.0f);  // row_bcast:15 -> rows 1,3
    x *= dpp_f<0x143, 0xc>(x, 1.0f);  // row_bcast:31 -> rows 2,3
    return x;
}
// inclusive add-scan over 64 lanes; lane 63 holds the full sum
__device__ __forceinline__ float scan_add(float x) {
    x += dpp_f<0x111, 0xf>(x, 0.0f);
    x += dpp_f<0x112, 0xf>(x, 0.0f);
    x += dpp_f<0x114, 0xf>(x, 0.0f);
    x += dpp_f<0x118, 0xf>(x, 0.0f);
    x += dpp_f<0x142, 0xa>(x, 0.0f);
    x += dpp_f<0x143, 0xc>(x, 0.0f);
    return x;
}

// 4-component wave reduction: every lane returns total of comp (lane&3).
__device__ __forceinline__ float quad_reduce4(float v0, float v1, float v2, float v3, int lane) {
    const bool b0 = (lane & 1) != 0;
    const float w01 = b0 ? v0 : v1, k01 = b0 ? v1 : v0;
    const float x01 = k01 + dpp_f<0xB1, 0xf>(w01, w01);   // quad_perm [1,0,3,2]
    const float w23 = b0 ? v2 : v3, k23 = b0 ? v3 : v2;
    const float x23 = k23 + dpp_f<0xB1, 0xf>(w23, w23);
    const bool b1 = (lane & 2) != 0;
    const float w = b1 ? x01 : x23, k = b1 ? x23 : x01;
    float x = k + dpp_f<0x4E, 0xf>(w, w);                 // quad_perm [2,3,0,1]
    x += dpp_f<0x124, 0xf>(x, x);                         // row_ror:4
    x += dpp_f<0x128, 0xf>(x, x);                         // row_ror:8
    x += swz_f<0x401F>(x);                                // xor16
    x += __shfl_xor(x, 32);
    return x;
}

__global__ __launch_bounds__(256) void nerf_render(
    const float* __restrict__ rays,      // (B,8)  o(3) d(3) near far
    const float* __restrict__ u_coarse,  // (B,64)
    const float* __restrict__ u_fine,    // (B,64)
    const float* __restrict__ u_jitter,  // (B,64)
    const float* __restrict__ W1,        // (3,32)
    const float* __restrict__ b1,        // (32,)
    const float* __restrict__ W2,        // (32,4)
    const float* __restrict__ b2,        // (4,)
    float* __restrict__ out)             // (B,8)  rgb_f, depth_f, rgb_c, depth_c
{
    __shared__ float4 w2q[32];       // W2 rows, block-shared           512B
    __shared__ float  acS[4][64];    // per wave: a[0..31], c[0..31]   1024B
    __shared__ float  zM[4][128];    // per wave merged z              2048B
    __shared__ f16x2v rgM[4][128];   // per wave merged (r,g)          2048B
    __shared__ f16x2v bsM[4][128];   // per wave merged (b,sigma)      2048B

    const int lane = threadIdx.x & 63;
    const int wv   = threadIdx.x >> 6;
    const int ray  = (blockIdx.x << 2) + wv;

    const float* rp = rays + ray * 8;
    const float ox = rp[0], oy = rp[1], oz = rp[2];
    const float ddx = rp[3], ddy = rp[4], ddz = rp[5];
    const float nearv = rp[6], farv = rp[7];

    // hoisted per-lane globals (one vmcnt covers all before first use)
    const float uc  = u_coarse[ray * 64 + lane];
    const float ufr = u_fine[ray * 64 + lane];
    const float uj  = u_jitter[ray * 64 + lane];

    // stage W2 rows into LDS (block-shared)
    if (threadIdx.x < 32) w2q[threadIdx.x] = reinterpret_cast<const float4*>(W2)[threadIdx.x];

    // cooperative a/c: lanes 0..31 -> a[j] = o@W1+b1, lanes 32..63 -> c[j] = d@W1
    {
        const int j = lane & 31;
        const float w0 = W1[j], w1 = W1[32 + j], w2 = W1[64 + j];
        const bool isA = lane < 32;
        const float px = isA ? ox : ddx;
        const float py = isA ? oy : ddy;
        const float pz = isA ? oz : ddz;
        const float bb = isA ? b1[j] : 0.0f;
        acS[wv][lane] = fmaf(px, w0, fmaf(py, w1, fmaf(pz, w2, bb)));
    }
    __syncthreads();  // covers w2q staging (once per kernel) + acS

    const float* aw = &acS[wv][0];
    const float* cw = &acS[wv][32];

    // h = relu(a + z*c) (32); out4 = h @ W2 + b2; rgb=sigmoid, sigma raw.
    auto mlp = [&](float z, float& rr, float& gg, float& bb_, float& sg) {
        const f32x2 zz = {z, z};
        const f32x2 zero2 = {0.0f, 0.0f};
        f32x2 acc01 = *reinterpret_cast<const f32x2*>(b2);
        f32x2 acc23 = *reinterpret_cast<const f32x2*>(b2 + 2);
#pragma unroll
        for (int j = 0; j < 32; j += 4) {
            const float4 av4 = *reinterpret_cast<const float4*>(aw + j);   // b128
            const float4 cv4 = *reinterpret_cast<const float4*>(cw + j);   // b128
            const f32x2 a01 = {av4.x, av4.y}, a23 = {av4.z, av4.w};
            const f32x2 c01 = {cv4.x, cv4.y}, c23 = {cv4.z, cv4.w};
            f32x2 h01 = __builtin_elementwise_fma(zz, c01, a01);
            f32x2 h23 = __builtin_elementwise_fma(zz, c23, a23);
            h01 = __builtin_elementwise_max(h01, zero2);
            h23 = __builtin_elementwise_max(h23, zero2);
            {
                const float4 wq = w2q[j + 0];                              // b128
                const f32x2 wA = {wq.x, wq.y}, wB = {wq.z, wq.w};
                const f32x2 hs = {h01.x, h01.x};
                acc01 = __builtin_elementwise_fma(hs, wA, acc01);
                acc23 = __builtin_elementwise_fma(hs, wB, acc23);
            }
            {
                const float4 wq = w2q[j + 1];
                const f32x2 wA = {wq.x, wq.y}, wB = {wq.z, wq.w};
                const f32x2 hs = {h01.y, h01.y};
                acc01 = __builtin_elementwise_fma(hs, wA, acc01);
                acc23 = __builtin_elementwise_fma(hs, wB, acc23);
            }
            {
                const float4 wq = w2q[j + 2];
                const f32x2 wA = {wq.x, wq.y}, wB = {wq.z, wq.w};
                const f32x2 hs = {h23.x, h23.x};
                acc01 = __builtin_elementwise_fma(hs, wA, acc01);
                acc23 = __builtin_elementwise_fma(hs, wB, acc23);
            }
            {
                const float4 wq = w2q[j + 3];
                const f32x2 wA = {wq.x, wq.y}, wB = {wq.z, wq.w};
                const f32x2 hs = {h23.y, h23.y};
                acc01 = __builtin_elementwise_fma(hs, wA, acc01);
                acc23 = __builtin_elementwise_fma(hs, wB, acc23);
            }
        }
        rr = fsigmoid(acc01.x); gg = fsigmoid(acc01.y);
        bb_ = fsigmoid(acc23.x); sg = acc23.y;
    };

    // ---------------- coarse pass ----------------
    const float zsc = (float)lane * 0.015625f + uc * 0.015625f;  // bit-match ref
    const float zc = nearv * (1.0f - zsc) + farv * zsc;

    const float zcn = dpp_f<0x130, 0xf>(zc, zc);  // wave_shl:1 (lane i <- i+1)
    const float deltac = (lane == 63) ? (farv - zc) : (zcn - zc);

    float cr_, cg_, cb_, csig;
    mlp(zc, cr_, cg_, cb_, csig);
    const float ec = __expf(-deltac * fmaxf(csig, 0.0f));
    const float alphac = 1.0f - ec;
    const float sc = ec + 1e-10f;

    // exclusive prefix product -> transmittance (DPP scan + wave_shr:1)
    const float pincl = scan_mul(sc);
    const float Tc = dpp_f<0x138, 0xf>(pincl, 1.0f);  // lane0 keeps 1.0
    const float wc = alphac * Tc;

    // coarse outputs: one transposed reduction (comp = lane&3)
    const float coarseTot = quad_reduce4(wc * cr_, wc * cg_, wc * cb_, wc * zc, lane);

    // ---------------- fine sampling (inverse CDF, unnormalized) ----------------
    const float wp = wc + 1e-5f;
    const float cdf = scan_add(wp);  // inclusive prefix sum
    const float tot = __int_as_float(__builtin_amdgcn_readlane(__float_as_int(cdf), 63));

    const float uf = ufr * tot;  // unnormalized space; uf < tot
    // cnt = #{k: cdf_incl[k] <= u} in [0,63] -> 6 steps, no guards
    int cnt = 0;
#pragma unroll
    for (int step = 32; step >= 1; step >>= 1) {
        const float v = __shfl(cdf, cnt + step - 1);
        if (v <= uf) cnt += step;
    }
    float key = (float)cnt + uj;  // == ref z_steps * 64 (bitwise)

    // ---------------- sort fine keys (bitonic, 64 lanes) ----------------
#pragma unroll
    for (int k = 2; k <= 64; k <<= 1) {
#pragma unroll
        for (int j = k >> 1; j > 0; j >>= 1) {
            float v;
            if (j == 1)       v = dpp_f<0xB1, 0xf>(key, key);   // quad_perm [1,0,3,2]
            else if (j == 2)  v = dpp_f<0x4E, 0xf>(key, key);   // quad_perm [2,3,0,1]
            else if (j == 4)  v = swz_f<0x101F>(key);           // ds_swizzle xor4
            else if (j == 8)  v = swz_f<0x201F>(key);           // xor8
            else if (j == 16) v = swz_f<0x401F>(key);           // xor16
            else              v = __shfl_xor(key, 32);
            const bool keepMin = (((lane & j) == 0) == ((lane & k) == 0));
            key = keepMin ? fminf(key, v) : fmaxf(key, v);
        }
    }

    // ---------------- analytic merge ranks (step-space) ----------------
    int cnti = (int)key; cnti = cnti > 63 ? 63 : cnti;
    const float ujr = key - (float)cnti;
    const float ucv = __shfl(uc, cnti);            // u_coarse[cnt'] (1 bpermute)
    const int g = cnti + ((ucv <= ujr) ? 1 : 0);   // fine k before coarse l <=> l >= g
    const int pos_f = lane + g;

    // pos_c = lane + #{k: g_k <= lane}. g is non-decreasing across lanes
    // (key sorted; equal cnti ordered by ujr; jumps bound g from below),
    // so a 6-step upper-bound search + count==64 fixup suffices.
    int cfv = 0;
#pragma unroll
    for (int step = 32; step >= 1; step >>= 1) {
        const int v = __shfl(g, cfv + step - 1);
        if (v <= lane) cfv += step;
    }
    const int g63 = __builtin_amdgcn_readlane(g, 63);
    if (cfv == 63 && g63 <= lane) cfv = 64;
    const int pos_c = lane + cfv;

    // fine z + MLP (coarse outputs reused, not recomputed)
    const float zsf = key * 0.015625f;
    const float zf = nearv * (1.0f - zsf) + farv * zsf;
    float fr_, fg_, fb_, fsig;
    mlp(zf, fr_, fg_, fb_, fsig);

    // ---------------- scatter merged (z f32; r,g,b,sigma f16) ----------------
    {
        zM[wv][pos_c] = zc;
        zM[wv][pos_f] = zf;
        f16x2v t;
        t.x = (_Float16)cr_;  t.y = (_Float16)cg_;  rgM[wv][pos_c] = t;
        t.x = (_Float16)fr_;  t.y = (_Float16)fg_;  rgM[wv][pos_f] = t;
        t.x = (_Float16)cb_;  t.y = (_Float16)csig; bsM[wv][pos_c] = t;
        t.x = (_Float16)fb_;  t.y = (_Float16)fsig; bsM[wv][pos_f] = t;
    }
    wave_fence();  // wave-private: scatter precedes gather in per-wave DS order

    // ---------------- fine composite (2 samples / lane) ----------------
    const float2 zz2 = *reinterpret_cast<const float2*>(&zM[wv][2 * lane]);
    const float z0 = zz2.x, z1 = zz2.y;
    const float z2n = dpp_f<0x130, 0xf>(z0, z0);  // z0 of lane+1 == elem 2*lane+2
    const f16x4v rg4 = *reinterpret_cast<const f16x4v*>(&rgM[wv][2 * lane]);
    const f16x4v bs4 = *reinterpret_cast<const f16x4v*>(&bsM[wv][2 * lane]);
    const float r0 = (float)rg4.x, g0 = (float)rg4.y;
    const float r1 = (float)rg4.z, g1 = (float)rg4.w;
    const float b0 = (float)bs4.x, s0 = (float)bs4.y;
    const float b1v = (float)bs4.z, s1 = (float)bs4.w;

    const float d0 = z1 - z0;
    const float d1 = (lane == 63) ? (farv - z1) : (z2n - z1);

    const float e0 = __expf(-d0 * fmaxf(s0, 0.0f));
    const float e1 = __expf(-d1 * fmaxf(s1, 0.0f));
    const float al0 = 1.0f - e0;
    const float al1 = 1.0f - e1;
    const float t0 = e0 + 1e-10f;
    const float t1 = e1 + 1e-10f;

    // pair product, DPP inclusive scan, exclusive via wave_shr:1
    const float ppincl = scan_mul(t0 * t1);
    const float Te = dpp_f<0x138, 0xf>(ppincl, 1.0f);  // lane0 keeps 1.0
    const float w0 = al0 * Te;
    const float w1 = al1 * (Te * t0);

    // fine outputs: one transposed reduction (comp = lane&3)
    const float fineTot = quad_reduce4(fmaf(w0, r0, w1 * r1), fmaf(w0, g0, w1 * g1),
                                       fmaf(w0, b0, w1 * b1v), fmaf(w0, z0, w1 * z1), lane);

    // out layout: [rgb_f, depth_f, rgb_c, depth_c]; lanes 0..7 store one dword
    if (lane < 8) {
        out[ray * 8 + lane] = (lane < 4) ? fineTot : coarseTot;
    }
}

extern "C" void kernel_launch(void* const* d_in, const int* in_sizes, int n_in,
                              void* d_out, int out_size, void* d_ws, size_t ws_size,
                              hipStream_t stream) {
    const float* rays     = (const float*)d_in[0];
    const float* u_coarse = (const float*)d_in[1];
    const float* u_fine   = (const float*)d_in[2];
    const float* u_jitter = (const float*)d_in[3];
    const float* W1       = (const float*)d_in[4];
    const float* b1       = (const float*)d_in[5];
    const float* W2       = (const float*)d_in[6];
    const float* b2       = (const float*)d_in[7];
    float* out = (float*)d_out;

    const int B = in_sizes[0] / 8;          // 65536
    dim3 grid(B / 4), block(256);           // one wave per ray, 4 waves/block
    hipLaunchKernelGGL(nerf_render, grid, block, 0, stream,
                       rays, u_coarse, u_fine, u_jitter, W1, b1, W2, b2, out);
}

// Round 11
// 196.460 us; speedup vs baseline: 1.0060x; 1.0060x over previous
//
#include <hip/hip_runtime.h>
#include <math.h>

// NeRF two-pass renderer. One wave (64 lanes) per ray; 4 waves per block.
// B=65536 rays, KC=64 coarse, KF=64 fine, HID=32.
//
// R11 = R8 backbone VERBATIM (W2 in LDS as f32x2[64] -> VGPR=32, occ 77%)
// + R9's two independently-validated pieces:
//  - pos_c via 6-step shuffle binary search over monotone g (no histogram,
//    no LDS atomics, no fences).
//  - z2n via DPP wave_shl:1 of z0 (no extra LDS read).
//  - uc/uf/uj global loads hoisted to kernel top.
// Everything else identical to R8 (6-step guardless searchsorted, bitonic
// with ds_swizzle immediates, quad-transposed output reductions, direct-exp
// alphas, f16-packed merge payload).
//
// HARD RULE learned R2/R9/R10: any form that lets the compiler hoist W2 into
// VGPRs (float4 LDS loads, SGPR-resident W2 with packed ops) explodes VGPR
// (76-136) and collapses occupancy. Keep the f32x2 LDS-read form.

typedef float f32x2 __attribute__((ext_vector_type(2)));
typedef _Float16 f16x2v __attribute__((ext_vector_type(2)));
typedef _Float16 f16x4v __attribute__((ext_vector_type(4)));

__device__ __forceinline__ float fast_rcp(float x) { return __builtin_amdgcn_rcpf(x); }
__device__ __forceinline__ float fsigmoid(float x) { return fast_rcp(1.0f + __expf(-x)); }

__device__ __forceinline__ f32x2 splat_lo(f32x2 v) { return __builtin_shufflevector(v, v, 0, 0); }
__device__ __forceinline__ f32x2 splat_hi(f32x2 v) { return __builtin_shufflevector(v, v, 1, 1); }

// compiler-only fence: no HW barrier; preserves LDS program order per wave
__device__ __forceinline__ void wave_fence() {
    asm volatile("" ::: "memory");
    __builtin_amdgcn_wave_barrier();
}

// DPP move: result = valid(src lane) ? shuffled x : oldv   (bound_ctrl=0)
template <int CTRL, int RMASK>
__device__ __forceinline__ float dpp_f(float x, float oldv) {
    return __int_as_float(__builtin_amdgcn_update_dpp(
        __float_as_int(oldv), __float_as_int(x), CTRL, RMASK, 0xf, false));
}
template <int OFF>
__device__ __forceinline__ float swz_f(float x) {
    return __int_as_float(__builtin_amdgcn_ds_swizzle(__float_as_int(x), OFF));
}

// inclusive multiply-scan over 64 lanes
__device__ __forceinline__ float scan_mul(float x) {
    x *= dpp_f<0x111, 0xf>(x, 1.0f);  // row_shr:1
    x *= dpp_f<0x112, 0xf>(x, 1.0f);  // row_shr:2
    x *= dpp_f<0x114, 0xf>(x, 1.0f);  // row_shr:4
    x *= dpp_f<0x118, 0xf>(x, 1.0f);  // row_shr:8
    x *= dpp_f<0x142, 0xa>(x, 1.0f);  // row_bcast:15 -> rows 1,3
    x *= dpp_f<0x143, 0xc>(x, 1.0f);  // row_bcast:31 -> rows 2,3
    return x;
}
// inclusive add-scan over 64 lanes; lane 63 holds the full sum
__device__ __forceinline__ float scan_add(float x) {
    x += dpp_f<0x111, 0xf>(x, 0.0f);
    x += dpp_f<0x112, 0xf>(x, 0.0f);
    x += dpp_f<0x114, 0xf>(x, 0.0f);
    x += dpp_f<0x118, 0xf>(x, 0.0f);
    x += dpp_f<0x142, 0xa>(x, 0.0f);
    x += dpp_f<0x143, 0xc>(x, 0.0f);
    return x;
}

// 4-component wave reduction: every lane returns total of comp (lane&3).
__device__ __forceinline__ float quad_reduce4(float v0, float v1, float v2, float v3, int lane) {
    const bool b0 = (lane & 1) != 0;
    const float w01 = b0 ? v0 : v1, k01 = b0 ? v1 : v0;
    const float x01 = k01 + dpp_f<0xB1, 0xf>(w01, w01);   // quad_perm [1,0,3,2]
    const float w23 = b0 ? v2 : v3, k23 = b0 ? v3 : v2;
    const float x23 = k23 + dpp_f<0xB1, 0xf>(w23, w23);
    const bool b1 = (lane & 2) != 0;
    const float w = b1 ? x01 : x23, k = b1 ? x23 : x01;
    float x = k + dpp_f<0x4E, 0xf>(w, w);                 // quad_perm [2,3,0,1]
    x += dpp_f<0x124, 0xf>(x, x);                         // row_ror:4
    x += dpp_f<0x128, 0xf>(x, x);                         // row_ror:8
    x += swz_f<0x401F>(x);                                // xor16
    x += __shfl_xor(x, 32);
    return x;
}

__global__ __launch_bounds__(256) void nerf_render(
    const float* __restrict__ rays,      // (B,8)  o(3) d(3) near far
    const float* __restrict__ u_coarse,  // (B,64)
    const float* __restrict__ u_fine,    // (B,64)
    const float* __restrict__ u_jitter,  // (B,64)
    const float* __restrict__ W1,        // (3,32)
    const float* __restrict__ b1,        // (32,)
    const float* __restrict__ W2,        // (32,4)
    const float* __restrict__ b2,        // (4,)
    float* __restrict__ out)             // (B,8)  rgb_f, depth_f, rgb_c, depth_c
{
    __shared__ f32x2  w2S[64];       // W2 pairs, block-shared          512B
    __shared__ float  acS[4][64];    // per wave: a[0..31], c[0..31]   1024B
    __shared__ float  zM[4][128];    // per wave merged z              2048B
    __shared__ f16x2v rgM[4][128];   // per wave merged (r,g)          2048B
    __shared__ f16x2v bsM[4][128];   // per wave merged (b,sigma)      2048B

    const int lane = threadIdx.x & 63;
    const int wv   = threadIdx.x >> 6;
    const int ray  = (blockIdx.x << 2) + wv;

    const float* rp = rays + ray * 8;
    const float ox = rp[0], oy = rp[1], oz = rp[2];
    const float ddx = rp[3], ddy = rp[4], ddz = rp[5];
    const float nearv = rp[6], farv = rp[7];

    // hoisted per-lane globals (one vmcnt window before first use)
    const float uc  = u_coarse[ray * 64 + lane];
    const float ufr = u_fine[ray * 64 + lane];
    const float uj  = u_jitter[ray * 64 + lane];

    // stage W2 into LDS (block-shared)
    if (threadIdx.x < 64) w2S[threadIdx.x] = reinterpret_cast<const f32x2*>(W2)[threadIdx.x];

    // cooperative a/c: lanes 0..31 -> a[j] = o@W1+b1, lanes 32..63 -> c[j] = d@W1
    {
        const int j = lane & 31;
        const float w0 = W1[j], w1 = W1[32 + j], w2 = W1[64 + j];
        const bool isA = lane < 32;
        const float px = isA ? ox : ddx;
        const float py = isA ? oy : ddy;
        const float pz = isA ? oz : ddz;
        const float bb = isA ? b1[j] : 0.0f;
        acS[wv][lane] = fmaf(px, w0, fmaf(py, w1, fmaf(pz, w2, bb)));
    }
    __syncthreads();  // covers w2S staging (once per kernel) + acS

    const float* aw = &acS[wv][0];
    const float* cw = &acS[wv][32];

    // h = relu(a + z*c) (32); out4 = h @ W2 + b2; rgb=sigmoid, sigma raw.
    // R8-verbatim form: f32x2 LDS reads, interleaved with FMAs (VGPR=32).
    auto mlp = [&](float z, float& rr, float& gg, float& bb_, float& sg) {
        const f32x2 zz = {z, z};
        const f32x2 zero2 = {0.0f, 0.0f};
        f32x2 acc01 = *reinterpret_cast<const f32x2*>(b2);
        f32x2 acc23 = *reinterpret_cast<const f32x2*>(b2 + 2);
#pragma unroll
        for (int j = 0; j < 32; j += 4) {
            const f32x2 a01 = *reinterpret_cast<const f32x2*>(aw + j);
            const f32x2 a23 = *reinterpret_cast<const f32x2*>(aw + j + 2);
            const f32x2 c01 = *reinterpret_cast<const f32x2*>(cw + j);
            const f32x2 c23 = *reinterpret_cast<const f32x2*>(cw + j + 2);
            f32x2 h01 = __builtin_elementwise_fma(zz, c01, a01);
            f32x2 h23 = __builtin_elementwise_fma(zz, c23, a23);
            h01 = __builtin_elementwise_max(h01, zero2);
            h23 = __builtin_elementwise_max(h23, zero2);
            {
                const f32x2 wA = w2S[(j + 0) * 2], wB = w2S[(j + 0) * 2 + 1];
                const f32x2 hs = splat_lo(h01);
                acc01 = __builtin_elementwise_fma(hs, wA, acc01);
                acc23 = __builtin_elementwise_fma(hs, wB, acc23);
            }
            {
                const f32x2 wA = w2S[(j + 1) * 2], wB = w2S[(j + 1) * 2 + 1];
                const f32x2 hs = splat_hi(h01);
                acc01 = __builtin_elementwise_fma(hs, wA, acc01);
                acc23 = __builtin_elementwise_fma(hs, wB, acc23);
            }
            {
                const f32x2 wA = w2S[(j + 2) * 2], wB = w2S[(j + 2) * 2 + 1];
                const f32x2 hs = splat_lo(h23);
                acc01 = __builtin_elementwise_fma(hs, wA, acc01);
                acc23 = __builtin_elementwise_fma(hs, wB, acc23);
            }
            {
                const f32x2 wA = w2S[(j + 3) * 2], wB = w2S[(j + 3) * 2 + 1];
                const f32x2 hs = splat_hi(h23);
                acc01 = __builtin_elementwise_fma(hs, wA, acc01);
                acc23 = __builtin_elementwise_fma(hs, wB, acc23);
            }
        }
        rr = fsigmoid(acc01.x); gg = fsigmoid(acc01.y);
        bb_ = fsigmoid(acc23.x); sg = acc23.y;
    };

    // ---------------- coarse pass ----------------
    const float zsc = (float)lane * 0.015625f + uc * 0.015625f;  // bit-match ref
    const float zc = nearv * (1.0f - zsc) + farv * zsc;

    const float zcn = dpp_f<0x130, 0xf>(zc, zc);  // wave_shl:1 (lane i <- i+1)
    const float deltac = (lane == 63) ? (farv - zc) : (zcn - zc);

    float cr_, cg_, cb_, csig;
    mlp(zc, cr_, cg_, cb_, csig);
    const float ec = __expf(-deltac * fmaxf(csig, 0.0f));
    const float alphac = 1.0f - ec;
    const float sc = ec + 1e-10f;

    // exclusive prefix product -> transmittance (DPP scan + wave_shr:1)
    const float pincl = scan_mul(sc);
    const float Tc = dpp_f<0x138, 0xf>(pincl, 1.0f);  // lane0 keeps 1.0
    const float wc = alphac * Tc;

    // coarse outputs: one transposed reduction (comp = lane&3)
    const float coarseTot = quad_reduce4(wc * cr_, wc * cg_, wc * cb_, wc * zc, lane);

    // ---------------- fine sampling (inverse CDF, unnormalized) ----------------
    const float wp = wc + 1e-5f;
    const float cdf = scan_add(wp);  // inclusive prefix sum
    const float tot = __int_as_float(__builtin_amdgcn_readlane(__float_as_int(cdf), 63));

    const float uf = ufr * tot;  // unnormalized space; uf < tot
    // cnt = #{k: cdf_incl[k] <= u} in [0,63] -> 6 steps, no guards
    int cnt = 0;
#pragma unroll
    for (int step = 32; step >= 1; step >>= 1) {
        const float v = __shfl(cdf, cnt + step - 1);
        if (v <= uf) cnt += step;
    }
    float key = (float)cnt + uj;  // == ref z_steps * 64 (bitwise)

    // ---------------- sort fine keys (bitonic, 64 lanes) ----------------
#pragma unroll
    for (int k = 2; k <= 64; k <<= 1) {
#pragma unroll
        for (int j = k >> 1; j > 0; j >>= 1) {
            float v;
            if (j == 1)       v = dpp_f<0xB1, 0xf>(key, key);   // quad_perm [1,0,3,2]
            else if (j == 2)  v = dpp_f<0x4E, 0xf>(key, key);   // quad_perm [2,3,0,1]
            else if (j == 4)  v = swz_f<0x101F>(key);           // ds_swizzle xor4
            else if (j == 8)  v = swz_f<0x201F>(key);           // xor8
            else if (j == 16) v = swz_f<0x401F>(key);           // xor16
            else              v = __shfl_xor(key, 32);
            const bool keepMin = (((lane & j) == 0) == ((lane & k) == 0));
            key = keepMin ? fminf(key, v) : fmaxf(key, v);
        }
    }

    // ---------------- analytic merge ranks (step-space) ----------------
    int cnti = (int)key; cnti = cnti > 63 ? 63 : cnti;
    const float ujr = key - (float)cnti;
    const float ucv = __shfl(uc, cnti);            // u_coarse[cnt'] (1 bpermute)
    const int g = cnti + ((ucv <= ujr) ? 1 : 0);   // fine k before coarse l <=> l >= g
    const int pos_f = lane + g;

    // pos_c = lane + #{k: g_k <= lane}. g is non-decreasing across lanes
    // (key sorted; equal cnti ordered by ujr; jumps bound g from below),
    // so a 6-step upper-bound search + count==64 fixup suffices.
    int cfv = 0;
#pragma unroll
    for (int step = 32; step >= 1; step >>= 1) {
        const int v = __shfl(g, cfv + step - 1);
        if (v <= lane) cfv += step;
    }
    const int g63 = __builtin_amdgcn_readlane(g, 63);
    if (cfv == 63 && g63 <= lane) cfv = 64;
    const int pos_c = lane + cfv;

    // fine z + MLP (coarse outputs reused, not recomputed)
    const float zsf = key * 0.015625f;
    const float zf = nearv * (1.0f - zsf) + farv * zsf;
    float fr_, fg_, fb_, fsig;
    mlp(zf, fr_, fg_, fb_, fsig);

    // ---------------- scatter merged (z f32; r,g,b,sigma f16) ----------------
    {
        zM[wv][pos_c] = zc;
        zM[wv][pos_f] = zf;
        f16x2v t;
        t.x = (_Float16)cr_;  t.y = (_Float16)cg_;  rgM[wv][pos_c] = t;
        t.x = (_Float16)fr_;  t.y = (_Float16)fg_;  rgM[wv][pos_f] = t;
        t.x = (_Float16)cb_;  t.y = (_Float16)csig; bsM[wv][pos_c] = t;
        t.x = (_Float16)fb_;  t.y = (_Float16)fsig; bsM[wv][pos_f] = t;
    }
    wave_fence();  // wave-private: scatter precedes gather in per-wave DS order

    // ---------------- fine composite (2 samples / lane) ----------------
    const float2 zz2 = *reinterpret_cast<const float2*>(&zM[wv][2 * lane]);
    const float z0 = zz2.x, z1 = zz2.y;
    const float z2n = dpp_f<0x130, 0xf>(z0, z0);  // z0 of lane+1 == elem 2*lane+2
    const f16x4v rg4 = *reinterpret_cast<const f16x4v*>(&rgM[wv][2 * lane]);
    const f16x4v bs4 = *reinterpret_cast<const f16x4v*>(&bsM[wv][2 * lane]);
    const float r0 = (float)rg4.x, g0 = (float)rg4.y;
    const float r1 = (float)rg4.z, g1 = (float)rg4.w;
    const float b0 = (float)bs4.x, s0 = (float)bs4.y;
    const float b1v = (float)bs4.z, s1 = (float)bs4.w;

    const float d0 = z1 - z0;
    const float d1 = (lane == 63) ? (farv - z1) : (z2n - z1);

    const float e0 = __expf(-d0 * fmaxf(s0, 0.0f));
    const float e1 = __expf(-d1 * fmaxf(s1, 0.0f));
    const float al0 = 1.0f - e0;
    const float al1 = 1.0f - e1;
    const float t0 = e0 + 1e-10f;
    const float t1 = e1 + 1e-10f;

    // pair product, DPP inclusive scan, exclusive via wave_shr:1
    const float ppincl = scan_mul(t0 * t1);
    const float Te = dpp_f<0x138, 0xf>(ppincl, 1.0f);  // lane0 keeps 1.0
    const float w0 = al0 * Te;
    const float w1 = al1 * (Te * t0);

    // fine outputs: one transposed reduction (comp = lane&3)
    const float fineTot = quad_reduce4(fmaf(w0, r0, w1 * r1), fmaf(w0, g0, w1 * g1),
                                       fmaf(w0, b0, w1 * b1v), fmaf(w0, z0, w1 * z1), lane);

    // out layout: [rgb_f, depth_f, rgb_c, depth_c]; lanes 0..7 store one dword
    if (lane < 8) {
        out[ray * 8 + lane] = (lane < 4) ? fineTot : coarseTot;
    }
}

extern "C" void kernel_launch(void* const* d_in, const int* in_sizes, int n_in,
                              void* d_out, int out_size, void* d_ws, size_t ws_size,
                              hipStream_t stream) {
    const float* rays     = (const float*)d_in[0];
    const float* u_coarse = (const float*)d_in[1];
    const float* u_fine   = (const float*)d_in[2];
    const float* u_jitter = (const float*)d_in[3];
    const float* W1       = (const float*)d_in[4];
    const float* b1       = (const float*)d_in[5];
    const float* W2       = (const float*)d_in[6];
    const float* b2       = (const float*)d_in[7];
    float* out = (float*)d_out;

    const int B = in_sizes[0] / 8;          // 65536
    dim3 grid(B / 4), block(256);           // one wave per ray, 4 waves/block
    hipLaunchKernelGGL(nerf_render, grid, block, 0, stream,
                       rays, u_coarse, u_fine, u_jitter, W1, b1, W2, b2, out);
}

// Round 12
// 75.639 us; speedup vs baseline: 2.6129x; 2.5973x over previous
//
#include <hip/hip_runtime.h>
#include <math.h>

// NeRF two-pass renderer. One wave (64 lanes) per ray; 4 waves per block.
// B=65536 rays, KC=64 coarse, KF=64 fine, HID=32.
//
// R12 = R8 source verbatim + three deltas:
//  1. pos_c via 6-step shuffle binary search over monotone g (R9-validated;
//     removes LDS histogram + 64 atomics).
//  2. z2n via DPP wave_shl:1 of z0 (no extra LDS read).
//  3. wave_fence() RIGHT BEFORE the fine mlp call.
//
// WHY #3 (R10/R11 lesson): without a memory clobber between the two mlp
// calls, the compiler CSEs the 64 w2S LDS loads across both calls and
// hoists all of W2 into 128 VGPRs (VGPR 32->136, occ 77%->11%, 2.4x
// slower). R8's histogram fences blocked that CSE by accident; this fence
// does it on purpose. Zero runtime cost (compiler-only barrier).

typedef float f32x2 __attribute__((ext_vector_type(2)));
typedef _Float16 f16x2v __attribute__((ext_vector_type(2)));
typedef _Float16 f16x4v __attribute__((ext_vector_type(4)));

__device__ __forceinline__ float fast_rcp(float x) { return __builtin_amdgcn_rcpf(x); }
__device__ __forceinline__ float fsigmoid(float x) { return fast_rcp(1.0f + __expf(-x)); }

__device__ __forceinline__ f32x2 splat_lo(f32x2 v) { return __builtin_shufflevector(v, v, 0, 0); }
__device__ __forceinline__ f32x2 splat_hi(f32x2 v) { return __builtin_shufflevector(v, v, 1, 1); }

// compiler-only fence: no HW barrier; preserves LDS program order per wave
// and blocks LDS-load CSE/hoisting across it (the VGPR guard).
__device__ __forceinline__ void wave_fence() {
    asm volatile("" ::: "memory");
    __builtin_amdgcn_wave_barrier();
}

// DPP move: result = valid(src lane) ? shuffled x : oldv   (bound_ctrl=0)
template <int CTRL, int RMASK>
__device__ __forceinline__ float dpp_f(float x, float oldv) {
    return __int_as_float(__builtin_amdgcn_update_dpp(
        __float_as_int(oldv), __float_as_int(x), CTRL, RMASK, 0xf, false));
}
template <int OFF>
__device__ __forceinline__ float swz_f(float x) {
    return __int_as_float(__builtin_amdgcn_ds_swizzle(__float_as_int(x), OFF));
}

// inclusive multiply-scan over 64 lanes
__device__ __forceinline__ float scan_mul(float x) {
    x *= dpp_f<0x111, 0xf>(x, 1.0f);  // row_shr:1
    x *= dpp_f<0x112, 0xf>(x, 1.0f);  // row_shr:2
    x *= dpp_f<0x114, 0xf>(x, 1.0f);  // row_shr:4
    x *= dpp_f<0x118, 0xf>(x, 1.0f);  // row_shr:8
    x *= dpp_f<0x142, 0xa>(x, 1.0f);  // row_bcast:15 -> rows 1,3
    x *= dpp_f<0x143, 0xc>(x, 1.0f);  // row_bcast:31 -> rows 2,3
    return x;
}
// inclusive add-scan over 64 lanes; lane 63 holds the full sum
__device__ __forceinline__ float scan_add(float x) {
    x += dpp_f<0x111, 0xf>(x, 0.0f);
    x += dpp_f<0x112, 0xf>(x, 0.0f);
    x += dpp_f<0x114, 0xf>(x, 0.0f);
    x += dpp_f<0x118, 0xf>(x, 0.0f);
    x += dpp_f<0x142, 0xa>(x, 0.0f);
    x += dpp_f<0x143, 0xc>(x, 0.0f);
    return x;
}

// 4-component wave reduction: every lane returns total of comp (lane&3).
__device__ __forceinline__ float quad_reduce4(float v0, float v1, float v2, float v3, int lane) {
    const bool b0 = (lane & 1) != 0;
    const float w01 = b0 ? v0 : v1, k01 = b0 ? v1 : v0;
    const float x01 = k01 + dpp_f<0xB1, 0xf>(w01, w01);   // quad_perm [1,0,3,2]
    const float w23 = b0 ? v2 : v3, k23 = b0 ? v3 : v2;
    const float x23 = k23 + dpp_f<0xB1, 0xf>(w23, w23);
    const bool b1 = (lane & 2) != 0;
    const float w = b1 ? x01 : x23, k = b1 ? x23 : x01;
    float x = k + dpp_f<0x4E, 0xf>(w, w);                 // quad_perm [2,3,0,1]
    x += dpp_f<0x124, 0xf>(x, x);                         // row_ror:4
    x += dpp_f<0x128, 0xf>(x, x);                         // row_ror:8
    x += swz_f<0x401F>(x);                                // xor16
    x += __shfl_xor(x, 32);
    return x;
}

__global__ __launch_bounds__(256) void nerf_render(
    const float* __restrict__ rays,      // (B,8)  o(3) d(3) near far
    const float* __restrict__ u_coarse,  // (B,64)
    const float* __restrict__ u_fine,    // (B,64)
    const float* __restrict__ u_jitter,  // (B,64)
    const float* __restrict__ W1,        // (3,32)
    const float* __restrict__ b1,        // (32,)
    const float* __restrict__ W2,        // (32,4)
    const float* __restrict__ b2,        // (4,)
    float* __restrict__ out)             // (B,8)  rgb_f, depth_f, rgb_c, depth_c
{
    __shared__ f32x2  w2S[64];       // W2 pairs, block-shared          512B
    __shared__ float  acS[4][64];    // per wave: a[0..31], c[0..31]   1024B
    __shared__ float  zM[4][128];    // per wave merged z              2048B
    __shared__ f16x2v rgM[4][128];   // per wave merged (r,g)          2048B
    __shared__ f16x2v bsM[4][128];   // per wave merged (b,sigma)      2048B

    const int lane = threadIdx.x & 63;
    const int wv   = threadIdx.x >> 6;
    const int ray  = (blockIdx.x << 2) + wv;

    const float* rp = rays + ray * 8;
    const float ox = rp[0], oy = rp[1], oz = rp[2];
    const float ddx = rp[3], ddy = rp[4], ddz = rp[5];
    const float nearv = rp[6], farv = rp[7];

    // stage W2 into LDS (block-shared), then one block barrier
    if (threadIdx.x < 64) w2S[threadIdx.x] = reinterpret_cast<const f32x2*>(W2)[threadIdx.x];

    // cooperative a/c: lanes 0..31 -> a[j] = o@W1+b1, lanes 32..63 -> c[j] = d@W1
    {
        const int j = lane & 31;
        const float w0 = W1[j], w1 = W1[32 + j], w2 = W1[64 + j];
        const bool isA = lane < 32;
        const float px = isA ? ox : ddx;
        const float py = isA ? oy : ddy;
        const float pz = isA ? oz : ddz;
        const float bb = isA ? b1[j] : 0.0f;
        acS[wv][lane] = fmaf(px, w0, fmaf(py, w1, fmaf(pz, w2, bb)));
    }
    __syncthreads();  // covers w2S staging (once per kernel) + acS

    const float* aw = &acS[wv][0];
    const float* cw = &acS[wv][32];

    // h = relu(a + z*c) (32); out4 = h @ W2 + b2; rgb=sigmoid, sigma raw.
    // R8-verbatim form: f32x2 LDS reads interleaved with FMAs (VGPR=32).
    auto mlp = [&](float z, float& rr, float& gg, float& bb_, float& sg) {
        const f32x2 zz = {z, z};
        const f32x2 zero2 = {0.0f, 0.0f};
        f32x2 acc01 = *reinterpret_cast<const f32x2*>(b2);
        f32x2 acc23 = *reinterpret_cast<const f32x2*>(b2 + 2);
#pragma unroll
        for (int j = 0; j < 32; j += 4) {
            const f32x2 a01 = *reinterpret_cast<const f32x2*>(aw + j);
            const f32x2 a23 = *reinterpret_cast<const f32x2*>(aw + j + 2);
            const f32x2 c01 = *reinterpret_cast<const f32x2*>(cw + j);
            const f32x2 c23 = *reinterpret_cast<const f32x2*>(cw + j + 2);
            f32x2 h01 = __builtin_elementwise_fma(zz, c01, a01);
            f32x2 h23 = __builtin_elementwise_fma(zz, c23, a23);
            h01 = __builtin_elementwise_max(h01, zero2);
            h23 = __builtin_elementwise_max(h23, zero2);
            {
                const f32x2 wA = w2S[(j + 0) * 2], wB = w2S[(j + 0) * 2 + 1];
                const f32x2 hs = splat_lo(h01);
                acc01 = __builtin_elementwise_fma(hs, wA, acc01);
                acc23 = __builtin_elementwise_fma(hs, wB, acc23);
            }
            {
                const f32x2 wA = w2S[(j + 1) * 2], wB = w2S[(j + 1) * 2 + 1];
                const f32x2 hs = splat_hi(h01);
                acc01 = __builtin_elementwise_fma(hs, wA, acc01);
                acc23 = __builtin_elementwise_fma(hs, wB, acc23);
            }
            {
                const f32x2 wA = w2S[(j + 2) * 2], wB = w2S[(j + 2) * 2 + 1];
                const f32x2 hs = splat_lo(h23);
                acc01 = __builtin_elementwise_fma(hs, wA, acc01);
                acc23 = __builtin_elementwise_fma(hs, wB, acc23);
            }
            {
                const f32x2 wA = w2S[(j + 3) * 2], wB = w2S[(j + 3) * 2 + 1];
                const f32x2 hs = splat_hi(h23);
                acc01 = __builtin_elementwise_fma(hs, wA, acc01);
                acc23 = __builtin_elementwise_fma(hs, wB, acc23);
            }
        }
        rr = fsigmoid(acc01.x); gg = fsigmoid(acc01.y);
        bb_ = fsigmoid(acc23.x); sg = acc23.y;
    };

    // ---------------- coarse pass ----------------
    const float uc = u_coarse[ray * 64 + lane];
    const float zsc = (float)lane * 0.015625f + uc * 0.015625f;  // bit-match ref
    const float zc = nearv * (1.0f - zsc) + farv * zsc;

    const float zcn = dpp_f<0x130, 0xf>(zc, zc);  // wave_shl:1 (lane i <- i+1)
    const float deltac = (lane == 63) ? (farv - zc) : (zcn - zc);

    float cr_, cg_, cb_, csig;
    mlp(zc, cr_, cg_, cb_, csig);
    const float ec = __expf(-deltac * fmaxf(csig, 0.0f));
    const float alphac = 1.0f - ec;
    const float sc = ec + 1e-10f;

    // exclusive prefix product -> transmittance (DPP scan + wave_shr:1)
    const float pincl = scan_mul(sc);
    const float Tc = dpp_f<0x138, 0xf>(pincl, 1.0f);  // lane0 keeps 1.0
    const float wc = alphac * Tc;

    // coarse outputs: one transposed reduction (comp = lane&3)
    const float coarseTot = quad_reduce4(wc * cr_, wc * cg_, wc * cb_, wc * zc, lane);

    // ---------------- fine sampling (inverse CDF, unnormalized) ----------------
    const float wp = wc + 1e-5f;
    const float cdf = scan_add(wp);  // inclusive prefix sum
    const float tot = __int_as_float(__builtin_amdgcn_readlane(__float_as_int(cdf), 63));

    const float uf = u_fine[ray * 64 + lane] * tot;  // unnormalized space; uf < tot
    // cnt = #{k: cdf_incl[k] <= u} in [0,63] -> 6 steps, no guards
    int cnt = 0;
#pragma unroll
    for (int step = 32; step >= 1; step >>= 1) {
        const float v = __shfl(cdf, cnt + step - 1);
        if (v <= uf) cnt += step;
    }
    const float uj = u_jitter[ray * 64 + lane];
    float key = (float)cnt + uj;  // == ref z_steps * 64 (bitwise)

    // ---------------- sort fine keys (bitonic, 64 lanes) ----------------
#pragma unroll
    for (int k = 2; k <= 64; k <<= 1) {
#pragma unroll
        for (int j = k >> 1; j > 0; j >>= 1) {
            float v;
            if (j == 1)       v = dpp_f<0xB1, 0xf>(key, key);   // quad_perm [1,0,3,2]
            else if (j == 2)  v = dpp_f<0x4E, 0xf>(key, key);   // quad_perm [2,3,0,1]
            else if (j == 4)  v = swz_f<0x101F>(key);           // ds_swizzle xor4
            else if (j == 8)  v = swz_f<0x201F>(key);           // xor8
            else if (j == 16) v = swz_f<0x401F>(key);           // xor16
            else              v = __shfl_xor(key, 32);
            const bool keepMin = (((lane & j) == 0) == ((lane & k) == 0));
            key = keepMin ? fminf(key, v) : fmaxf(key, v);
        }
    }

    // ---------------- analytic merge ranks (step-space) ----------------
    int cnti = (int)key; cnti = cnti > 63 ? 63 : cnti;
    const float ujr = key - (float)cnti;
    const float ucv = __shfl(uc, cnti);            // u_coarse[cnt'] (1 bpermute)
    const int g = cnti + ((ucv <= ujr) ? 1 : 0);   // fine k before coarse l <=> l >= g
    const int pos_f = lane + g;

    // pos_c = lane + #{k: g_k <= lane}. g is non-decreasing across lanes
    // (key sorted; equal cnti ordered by ujr; jumps bound g from below),
    // so a 6-step upper-bound search + count==64 fixup suffices.
    int cfv = 0;
#pragma unroll
    for (int step = 32; step >= 1; step >>= 1) {
        const int v = __shfl(g, cfv + step - 1);
        if (v <= lane) cfv += step;
    }
    const int g63 = __builtin_amdgcn_readlane(g, 63);
    if (cfv == 63 && g63 <= lane) cfv = 64;
    const int pos_c = lane + cfv;

    // fine z (coarse outputs reused, not recomputed)
    const float zsf = key * 0.015625f;
    const float zf = nearv * (1.0f - zsf) + farv * zsf;

    wave_fence();  // ANTI-CSE GUARD: block w2S/acS load reuse across mlp calls
                   // (without this: VGPR 32->136, occupancy 77%->11%, 2.4x slow)

    float fr_, fg_, fb_, fsig;
    mlp(zf, fr_, fg_, fb_, fsig);

    // ---------------- scatter merged (z f32; r,g,b,sigma f16) ----------------
    {
        zM[wv][pos_c] = zc;
        zM[wv][pos_f] = zf;
        f16x2v t;
        t.x = (_Float16)cr_;  t.y = (_Float16)cg_;  rgM[wv][pos_c] = t;
        t.x = (_Float16)fr_;  t.y = (_Float16)fg_;  rgM[wv][pos_f] = t;
        t.x = (_Float16)cb_;  t.y = (_Float16)csig; bsM[wv][pos_c] = t;
        t.x = (_Float16)fb_;  t.y = (_Float16)fsig; bsM[wv][pos_f] = t;
    }
    wave_fence();  // wave-private: scatter precedes gather in per-wave DS order

    // ---------------- fine composite (2 samples / lane) ----------------
    const float2 zz2 = *reinterpret_cast<const float2*>(&zM[wv][2 * lane]);
    const float z0 = zz2.x, z1 = zz2.y;
    const float z2n = dpp_f<0x130, 0xf>(z0, z0);  // z0 of lane+1 == elem 2*lane+2
    const f16x4v rg4 = *reinterpret_cast<const f16x4v*>(&rgM[wv][2 * lane]);
    const f16x4v bs4 = *reinterpret_cast<const f16x4v*>(&bsM[wv][2 * lane]);
    const float r0 = (float)rg4.x, g0 = (float)rg4.y;
    const float r1 = (float)rg4.z, g1 = (float)rg4.w;
    const float b0 = (float)bs4.x, s0 = (float)bs4.y;
    const float b1v = (float)bs4.z, s1 = (float)bs4.w;

    const float d0 = z1 - z0;
    const float d1 = (lane == 63) ? (farv - z1) : (z2n - z1);

    const float e0 = __expf(-d0 * fmaxf(s0, 0.0f));
    const float e1 = __expf(-d1 * fmaxf(s1, 0.0f));
    const float al0 = 1.0f - e0;
    const float al1 = 1.0f - e1;
    const float t0 = e0 + 1e-10f;
    const float t1 = e1 + 1e-10f;

    // pair product, DPP inclusive scan, exclusive via wave_shr:1
    const float ppincl = scan_mul(t0 * t1);
    const float Te = dpp_f<0x138, 0xf>(ppincl, 1.0f);  // lane0 keeps 1.0
    const float w0 = al0 * Te;
    const float w1 = al1 * (Te * t0);

    // fine outputs: one transposed reduction (comp = lane&3)
    const float fineTot = quad_reduce4(fmaf(w0, r0, w1 * r1), fmaf(w0, g0, w1 * g1),
                                       fmaf(w0, b0, w1 * b1v), fmaf(w0, z0, w1 * z1), lane);

    // out layout: [rgb_f, depth_f, rgb_c, depth_c]; lanes 0..7 store one dword
    if (lane < 8) {
        out[ray * 8 + lane] = (lane < 4) ? fineTot : coarseTot;
    }
}

extern "C" void kernel_launch(void* const* d_in, const int* in_sizes, int n_in,
                              void* d_out, int out_size, void* d_ws, size_t ws_size,
                              hipStream_t stream) {
    const float* rays     = (const float*)d_in[0];
    const float* u_coarse = (const float*)d_in[1];
    const float* u_fine   = (const float*)d_in[2];
    const float* u_jitter = (const float*)d_in[3];
    const float* W1       = (const float*)d_in[4];
    const float* b1       = (const float*)d_in[5];
    const float* W2       = (const float*)d_in[6];
    const float* b2       = (const float*)d_in[7];
    float* out = (float*)d_out;

    const int B = in_sizes[0] / 8;          // 65536
    dim3 grid(B / 4), block(256);           // one wave per ray, 4 waves/block
    hipLaunchKernelGGL(nerf_render, grid, block, 0, stream,
                       rays, u_coarse, u_fine, u_jitter, W1, b1, W2, b2, out);
}